// Round 17
// baseline (93.138 us; speedup 1.0000x reference)
//
#include <hip/hip_runtime.h>
#include <math.h>

#define N_ 16
#define T_ 8192
#define C_ 128
#define K_ 64

#define TPB_A 64       // t per fused block
#define BPN_A 128      // fused blocks per n

// ws layout in floats (100.7 MB; ws proven 268 MB by harness poison fills)
#define NW_ASUM 0              // 1024
#define NW_MCS  2048           // N*C = 2048 -> 4096  (masked colsum)
#define NW_ZBYTES (4096 * 4)   // memset region covers asum+mcs
#define NW_W2F  4096           // 4096 floats (8192 bf16)
#define NW_P1   8192           // 512 -> 8704, pad to 8960
#define NW_XTM  8960           // N*T*C bf16 = 8388608 floats -> 8397568
#define NW_PART 8397568        // N*BPN_A*K*C = 16777216 floats -> 25174784
#define NW_TOTAL 25174784

typedef __attribute__((ext_vector_type(8))) short short8;
typedef __attribute__((ext_vector_type(4))) float f32x4;

__device__ __forceinline__ uint bfr(float f) {          // fp32 -> bf16 (RNE)
    uint u = __float_as_uint(f);
    return (u + 0x7fffu + ((u >> 16) & 1u)) >> 16;
}
__device__ __forceinline__ uint pack2(float lo, float hi) {
    return bfr(lo) | (bfr(hi) << 16);
}
__device__ __forceinline__ float bfu(ushort u) {
    return __uint_as_float(((uint)u) << 16);
}

// Normalize rows, emit xn bf16 t-minor chunks [chunk=32t][128c][32t] (chunks
// up to Lb + halo), accumulate masked-region (t >= Lb) colsum into mcs.
// Blocks 0..3 additionally build the w2 fragment table + conv1/bn1 params
// (consumed only by fused_k, which launches after this kernel completes).
__global__ __launch_bounds__(256, 8) void xnorm_k(
    const float* __restrict__ x, ushort* __restrict__ xtm,
    const int* __restrict__ length, float* __restrict__ mcs,
    const float* __restrict__ conv1_w,
    const float* __restrict__ bn1_g, const float* __restrict__ bn1_b,
    const float* __restrict__ bn1_m, const float* __restrict__ bn1_v,
    const float* __restrict__ conv2_w,
    const float* __restrict__ bn2_g, const float* __restrict__ bn2_v,
    ushort* __restrict__ w2t, float* __restrict__ p1) {
    __shared__ uint xt[32][64];            // packed c-pairs, [t][c2]
    const int tid = threadIdx.x;
    const int lane = tid & 63;
    const int w = tid >> 6;
    const int n = blockIdx.x >> 8;
    const int tloc = (blockIdx.x & 255) * 32;
    const size_t row0 = (size_t)blockIdx.x * 32;
    const int L = length[n];
    const int Lb = ((L + 63) >> 6) << 6;   // live-block coverage [0, Lb)

    // ---- setup (blocks 0..3): constant tables for fused_k ----
    if (blockIdx.x < 4) {
        const int gt = blockIdx.x * 256 + tid;   // 0..1023
        for (int idx = gt; idx < 8192; idx += 1024) {
            int j = idx & 7;
            int ln = (idx >> 3) & 63;
            int mq = idx >> 9;
            int m = mq >> 2, q = mq & 3;
            int fr = ln & 15, fg = ln >> 4;
            int k = m * 16 + fr;
            float sck = bn2_g[k] * rsqrtf(bn2_v[k] + 1e-5f);
            float v = conv2_w[k * C_ + q * 32 + fg * 8 + j] * sck;
            w2t[idx] = (ushort)bfr(v);
        }
        for (int c = gt; c < C_; c += 1024) {
            float s1 = bn1_g[c] * rsqrtf(bn1_v[c] + 1e-5f);
            p1[c]       = conv1_w[c * 9 + 1] * s1;
            p1[128 + c] = conv1_w[c * 9 + 4] * s1;
            p1[256 + c] = conv1_w[c * 9 + 7] * s1;
            p1[384 + c] = bn1_b[c] - bn1_m[c] * s1;
        }
    }

#pragma unroll
    for (int i = 0; i < 8; ++i) {
        int r = w * 8 + i;
        const float* xr = x + (row0 + r) * C_;
        float2 v = *(const float2*)&xr[lane * 2];
        float ss = v.x * v.x + v.y * v.y;
#pragma unroll
        for (int m = 1; m < 64; m <<= 1) ss += __shfl_xor(ss, m, 64);
        float rn = 1.0f / fmaxf(sqrtf(ss), 1e-12f);
        xt[r][lane] = pack2(v.x * rn, v.y * rn);
    }
    __syncthreads();

    if (tloc <= Lb) {
        // consumed by fused kernel (conv halo reaches chunk Lb/32): store it
        uint4* dst = (uint4*)(xtm + (size_t)blockIdx.x * 4096);
#pragma unroll
        for (int uu = 0; uu < 2; ++uu) {
            int u = tid * 2 + uu;              // 0..511
            int c = u >> 2, j = u & 3;
            int cw = c >> 1, sh = (c & 1) * 16;
            uint o[4];
#pragma unroll
            for (int q = 0; q < 4; ++q) {
                uint lo = (xt[j * 8 + q * 2][cw] >> sh) & 0xffffu;
                uint hi = (xt[j * 8 + q * 2 + 1][cw] >> sh) & 0xffffu;
                o[q] = lo | (hi << 16);
            }
            uint4 v; v.x = o[0]; v.y = o[1]; v.z = o[2]; v.w = o[3];
            dst[u] = v;
        }
    }
    if (tloc >= Lb && w == 0) {
        // analytic masked region [Lb, T): contribution = mcs/64
        float sx = 0.f, sy = 0.f;
#pragma unroll 8
        for (int r = 0; r < 32; ++r) {
            uint u = xt[r][lane];
            sx += bfu((ushort)(u & 0xffffu));
            sy += bfu((ushort)(u >> 16));
        }
        atomicAdd(&mcs[n * C_ + lane * 2], sx);
        atomicAdd(&mcs[n * C_ + lane * 2 + 1], sy);
    }
}

// Fused: conv -> logits MFMA -> softmax -> a in LDS -> vlad MFMA (af from LDS,
// bfv from xtm/L2) -> private partials. One 64-t super-tile per block.
// n-fast index: live blocks (blk < ceil(L/64)) occupy the low grid range.
__global__ __launch_bounds__(256, 3) void fused_k(
    const ushort* __restrict__ xtm,
    const float* __restrict__ conv2_b,
    const float* __restrict__ bn2_g, const float* __restrict__ bn2_b,
    const float* __restrict__ bn2_m, const float* __restrict__ bn2_v,
    const int* __restrict__ length,
    const ushort* __restrict__ w2t, const float* __restrict__ p1,
    float* __restrict__ part, float* __restrict__ asum) {

    __shared__ __align__(16) ushort w2l[8192];           // 16 KB
    __shared__ __align__(16) ushort h_s[4][16 * 136];    // 17.4 KB
    __shared__ __align__(16) uint4 ab[2][64 * 5];        // 10.2 KB

    const int tid = threadIdx.x;
    const int lane = tid & 63;
    const int w = tid >> 6;
    const int fr = lane & 15, fg = lane >> 4;
    const int tile = w >> 1, half = w & 1;
    const int n = blockIdx.x & (N_ - 1);     // n-fast
    const int blk = blockIdx.x >> 4;
    const int tb = blk * TPB_A;
    const int L = length[n];
    if (tb >= L) return;                   // analytic region (mcs)

    const ushort* xtm_n = xtm + (size_t)n * 256 * 4096;

    {
        const uint4* w2g = (const uint4*)w2t;
        uint4* w2d = (uint4*)w2l;
#pragma unroll
        for (int i = 0; i < 4; ++i) w2d[tid + i * 256] = w2g[tid + i * 256];
    }

    float wa[2], wbv[2], wcv[2], sbv[2];
#pragma unroll
    for (int p = 0; p < 2; ++p) {
        int c = lane + p * 64;
        wa[p] = p1[c]; wbv[p] = p1[128 + c];
        wcv[p] = p1[256 + c]; sbv[p] = p1[384 + c];
    }

    float sh2r[16];
#pragma unroll
    for (int m = 0; m < 4; ++m)
#pragma unroll
        for (int r = 0; r < 4; ++r) {
            int k = m * 16 + fg * 4 + r;
            float s = bn2_g[k] * rsqrtf(bn2_v[k] + 1e-5f);
            sh2r[m * 4 + r] = s * conv2_b[k] + bn2_b[k] - bn2_m[k] * s;
        }

    short8 onesf;
    {
        short f = (fr == 0) ? (short)0x3F80 : (short)0;
#pragma unroll
        for (int j = 0; j < 8; ++j) onesf[j] = f;
    }

    f32x4 accB[9];
#pragma unroll
    for (int cb = 0; cb < 9; ++cb) accB[cb] = (f32x4){0.f, 0.f, 0.f, 0.f};

    __syncthreads();

    {
        const int tcs = (tb >> 5) + tile;
        const ushort* xch = xtm_n + (size_t)tcs * 4096;
        const int t0 = tb + tile * 32 + half * 16;

        if (t0 < L) {
            // ---- conv: lane owns c = lane, lane+64; 16 t in registers ----
            ushort* hw = h_s[w];
#pragma unroll
            for (int p = 0; p < 2; ++p) {
                const int c = lane + p * 64;
                short8 x0 = *(const short8*)&xch[c * 32 + half * 16];
                short8 x1 = *(const short8*)&xch[c * 32 + half * 16 + 8];
                float av[18];
                av[0] = 0.f; av[17] = 0.f;
                if (t0 > 0)
                    av[0] = bfu(half ? xch[c * 32 + 15] : xch[c * 32 - 4096 + 31]);
                if (t0 + 16 < T_)
                    av[17] = bfu(half ? xch[c * 32 + 4096] : xch[c * 32 + 16]);
#pragma unroll
                for (int j = 0; j < 8; ++j) {
                    av[1 + j] = bfu((ushort)x0[j]);
                    av[9 + j] = bfu((ushort)x1[j]);
                }
                float WA = wa[p], WB = wbv[p], WC = wcv[p], SB = sbv[p];
#pragma unroll
                for (int j = 0; j < 16; ++j)
                    hw[j * 136 + c] = (ushort)bfr(
                        fmaxf(0.f, av[j] * WA + av[j + 1] * WB + av[j + 2] * WC + SB));
            }
            // ---- logits MFMA (w2 from LDS; all 16 B-columns real) ----
            f32x4 accL[4];
#pragma unroll
            for (int m = 0; m < 4; ++m) accL[m] = (f32x4){0.f, 0.f, 0.f, 0.f};
            const ushort* hbp = h_s[w] + fr * 136 + fg * 8;
#pragma unroll
            for (int q = 0; q < 4; ++q) {
                short8 hf = *(const short8*)(hbp + q * 32);
                short8 w0 = *(const short8*)&w2l[((0 * 4 + q) * 64 + lane) * 8];
                short8 w1 = *(const short8*)&w2l[((1 * 4 + q) * 64 + lane) * 8];
                short8 w2f = *(const short8*)&w2l[((2 * 4 + q) * 64 + lane) * 8];
                short8 w3 = *(const short8*)&w2l[((3 * 4 + q) * 64 + lane) * 8];
                accL[0] = __builtin_amdgcn_mfma_f32_16x16x32_bf16(w0, hf, accL[0], 0, 0, 0);
                accL[1] = __builtin_amdgcn_mfma_f32_16x16x32_bf16(w1, hf, accL[1], 0, 0, 0);
                accL[2] = __builtin_amdgcn_mfma_f32_16x16x32_bf16(w2f, hf, accL[2], 0, 0, 0);
                accL[3] = __builtin_amdgcn_mfma_f32_16x16x32_bf16(w3, hf, accL[3], 0, 0, 0);
            }
            // ---- bn2 + relu + mask + softmax over k (t = t0 + fr, all lanes) ----
            {
                int t = t0 + fr;
                float v[16];
#pragma unroll
                for (int m = 0; m < 4; ++m)
#pragma unroll
                    for (int r = 0; r < 4; ++r)
                        v[m * 4 + r] = fmaxf(0.f, accL[m][r] + sh2r[m * 4 + r]);
                if (t < L) {
                    float mx = v[0];
#pragma unroll
                    for (int i = 1; i < 16; ++i) mx = fmaxf(mx, v[i]);
                    mx = fmaxf(mx, __shfl_xor(mx, 16, 64));
                    mx = fmaxf(mx, __shfl_xor(mx, 32, 64));
                    float se = 0.f;
#pragma unroll
                    for (int i = 0; i < 16; ++i) { v[i] = __expf(v[i] - mx); se += v[i]; }
                    se += __shfl_xor(se, 16, 64);
                    se += __shfl_xor(se, 32, 64);
                    float inv = 1.0f / se;
#pragma unroll
                    for (int i = 0; i < 16; ++i) v[i] *= inv;
                } else {
#pragma unroll
                    for (int i = 0; i < 16; ++i) v[i] = 0.015625f;
                }
                const int jq = half * 2 + (fr >> 3);
                const int te = fr & 7;
#pragma unroll
                for (int m = 0; m < 4; ++m)
#pragma unroll
                    for (int r = 0; r < 4; ++r) {
                        int k = m * 16 + fg * 4 + r;
                        ((ushort*)&ab[tile][k * 5 + jq])[te] = (ushort)bfr(v[m * 4 + r]);
                    }
            }
        } else {
            // masked wave (t in [L, Lb)): a = 1/64 exactly (2 quads)
            uint4 cfill;
            cfill.x = cfill.y = cfill.z = cfill.w = 0x3C803C80u;
            ab[tile][lane * 5 + half * 2] = cfill;
            ab[tile][lane * 5 + half * 2 + 1] = cfill;
        }
        __syncthreads();
        // ---- vlad MFMA: af from LDS, bfv from xtm (L2-hot) ----
#pragma unroll
        for (int cc = 0; cc < 2; ++cc) {
            const ushort* xc2 = xtm_n + (size_t)((tb >> 5) + cc) * 4096;
            short8 af = *(const short8*)&ab[cc][(w * 16 + fr) * 5 + fg];
#pragma unroll
            for (int cb = 0; cb < 8; ++cb) {
                short8 bfv = *(const short8*)&xc2[(cb * 16 + fr) * 32 + fg * 8];
                accB[cb] = __builtin_amdgcn_mfma_f32_16x16x32_bf16(af, bfv, accB[cb], 0, 0, 0);
            }
            accB[8] = __builtin_amdgcn_mfma_f32_16x16x32_bf16(af, onesf, accB[8], 0, 0, 0);
        }
    }

    float* pr = part + (size_t)(n * BPN_A + blk) * (K_ * C_);
#pragma unroll
    for (int cb = 0; cb < 8; ++cb)
#pragma unroll
        for (int r = 0; r < 4; ++r)
            pr[(w * 16 + fg * 4 + r) * C_ + cb * 16 + fr] = accB[cb][r];
    if (fr == 0) {
#pragma unroll
        for (int r = 0; r < 4; ++r)
            atomicAdd(&asum[n * K_ + w * 16 + fg * 4 + r], accB[8][r]);
    }
}

// fused reduce + finalize: live partials + analytic masked term, intra-norm,
// analytic global norm (K unit rows -> 1/sqrt(K) = 1/8 folded in).
__global__ void finalize2_k(const float* __restrict__ cent,
                            const float* __restrict__ part,
                            const float* __restrict__ asum,
                            const float* __restrict__ mcs,
                            const int* __restrict__ length,
                            float* __restrict__ out) {
    int row = blockIdx.x * 4 + (threadIdx.x >> 6);  // n*64 + k
    int lane = threadIdx.x & 63;
    int n = row >> 6, k = row & 63;
    const int L = length[n];
    const int nlive = (L + 63) >> 6;       // live fused blocks
    const float* pr = part + (size_t)n * BPN_A * (K_ * C_) + k * C_;
    float y0 = 0.f, y1 = 0.f;
#pragma unroll 4
    for (int b = 0; b < nlive; ++b) {
        y0 += pr[(size_t)b * (K_ * C_) + lane];
        y1 += pr[(size_t)b * (K_ * C_) + lane + 64];
    }
    y0 += 0.015625f * mcs[n * C_ + lane];
    y1 += 0.015625f * mcs[n * C_ + lane + 64];
    float as = asum[row] + (float)(T_ - nlive * TPB_A) * 0.015625f;
    y0 -= as * cent[k * C_ + lane];
    y1 -= as * cent[k * C_ + lane + 64];
    float ss = y0 * y0 + y1 * y1;
#pragma unroll
    for (int m = 1; m < 64; m <<= 1) ss += __shfl_xor(ss, m, 64);
    float rs = 0.125f / fmaxf(sqrtf(ss), 1e-12f);   // intra-norm x global 1/8
    out[(size_t)row * C_ + lane] = y0 * rs;
    out[(size_t)row * C_ + lane + 64] = y1 * rs;
}

extern "C" void kernel_launch(void* const* d_in, const int* in_sizes, int n_in,
                              void* d_out, int out_size, void* d_ws, size_t ws_size,
                              hipStream_t stream) {
    const float* x       = (const float*)d_in[0];
    const float* conv1_w = (const float*)d_in[1];
    const float* bn1_g   = (const float*)d_in[2];
    const float* bn1_b   = (const float*)d_in[3];
    const float* bn1_m   = (const float*)d_in[4];
    const float* bn1_v   = (const float*)d_in[5];
    const float* conv2_w = (const float*)d_in[6];
    const float* conv2_b = (const float*)d_in[7];
    const float* bn2_g   = (const float*)d_in[8];
    const float* bn2_b   = (const float*)d_in[9];
    const float* bn2_m   = (const float*)d_in[10];
    const float* bn2_v   = (const float*)d_in[11];
    const float* cent    = (const float*)d_in[12];
    const int*   length  = (const int*)d_in[13];
    float* out = (float*)d_out;
    float* ws  = (float*)d_ws;

    hipMemsetAsync(ws, 0, NW_ZBYTES, stream);  // zero asum + mcs
    xnorm_k<<<N_ * T_ / 32, 256, 0, stream>>>(
        x, (ushort*)(ws + NW_XTM), length, ws + NW_MCS,
        conv1_w, bn1_g, bn1_b, bn1_m, bn1_v, conv2_w, bn2_g, bn2_v,
        (ushort*)(ws + NW_W2F), ws + NW_P1);
    fused_k<<<N_ * BPN_A, 256, 0, stream>>>(
        (const ushort*)(ws + NW_XTM), conv2_b, bn2_g, bn2_b, bn2_m, bn2_v,
        length, (const ushort*)(ws + NW_W2F), ws + NW_P1,
        ws + NW_PART, ws + NW_ASUM);
    finalize2_k<<<(N_ * K_) / 4, 256, 0, stream>>>(
        cent, ws + NW_PART, ws + NW_ASUM, ws + NW_MCS, length, out);
}

// Round 18
// 79.365 us; speedup vs baseline: 1.1735x; 1.1735x over previous
//
#include <hip/hip_runtime.h>
#include <math.h>

#define N_ 16
#define T_ 8192
#define C_ 128
#define K_ 64

#define TPB_A 128      // t per fused block
#define BPN_A 64       // fused blocks per n

// ws layout in floats (67.15 MB; ws proven 268 MB by harness poison fills)
#define NW_ASUM 0              // 1024
#define NW_MCS  2048           // N*C = 2048 -> 4096  (masked colsum)
#define NW_ZBYTES (4096 * 4)   // memset region covers asum+mcs
#define NW_W2F  4096           // 4096 floats (8192 bf16)
#define NW_P1   8192           // 512 -> 8704, pad to 8960
#define NW_XTM  8960           // N*T*C bf16 = 8388608 floats -> 8397568
#define NW_PART 8397568        // N*BPN_A*K*C = 8388608 floats -> 16786176
#define NW_TOTAL 16786176

typedef __attribute__((ext_vector_type(8))) short short8;
typedef __attribute__((ext_vector_type(4))) float f32x4;

__device__ __forceinline__ uint bfr(float f) {          // fp32 -> bf16 (RNE)
    uint u = __float_as_uint(f);
    return (u + 0x7fffu + ((u >> 16) & 1u)) >> 16;
}
__device__ __forceinline__ uint pack2(float lo, float hi) {
    return bfr(lo) | (bfr(hi) << 16);
}
__device__ __forceinline__ float bfu(ushort u) {
    return __uint_as_float(((uint)u) << 16);
}

// Normalize rows, emit xn bf16 t-minor chunks [chunk=32t][128c][32t] (chunks
// up to Lb + halo), accumulate masked-region (t >= Lb) colsum into mcs.
// Blocks 0..3 additionally build the w2 fragment table + conv1/bn1 params
// (consumed only by fused_k, which launches after this kernel completes).
__global__ __launch_bounds__(256, 8) void xnorm_k(
    const float* __restrict__ x, ushort* __restrict__ xtm,
    const int* __restrict__ length, float* __restrict__ mcs,
    const float* __restrict__ conv1_w,
    const float* __restrict__ bn1_g, const float* __restrict__ bn1_b,
    const float* __restrict__ bn1_m, const float* __restrict__ bn1_v,
    const float* __restrict__ conv2_w,
    const float* __restrict__ bn2_g, const float* __restrict__ bn2_v,
    ushort* __restrict__ w2t, float* __restrict__ p1) {
    __shared__ uint xt[32][64];            // packed c-pairs, [t][c2]
    const int tid = threadIdx.x;
    const int lane = tid & 63;
    const int w = tid >> 6;
    const int n = blockIdx.x >> 8;
    const int tloc = (blockIdx.x & 255) * 32;
    const size_t row0 = (size_t)blockIdx.x * 32;
    const int L = length[n];
    const int Lb = ((L + 127) >> 7) << 7;  // live-block coverage [0, Lb)

    // ---- setup (blocks 0..3): constant tables for fused_k ----
    if (blockIdx.x < 4) {
        const int gt = blockIdx.x * 256 + tid;   // 0..1023
        for (int idx = gt; idx < 8192; idx += 1024) {
            int j = idx & 7;
            int ln = (idx >> 3) & 63;
            int mq = idx >> 9;
            int m = mq >> 2, q = mq & 3;
            int fr = ln & 15, fg = ln >> 4;
            int k = m * 16 + fr;
            float sck = bn2_g[k] * rsqrtf(bn2_v[k] + 1e-5f);
            float v = conv2_w[k * C_ + q * 32 + fg * 8 + j] * sck;
            w2t[idx] = (ushort)bfr(v);
        }
        for (int c = gt; c < C_; c += 1024) {
            float s1 = bn1_g[c] * rsqrtf(bn1_v[c] + 1e-5f);
            p1[c]       = conv1_w[c * 9 + 1] * s1;
            p1[128 + c] = conv1_w[c * 9 + 4] * s1;
            p1[256 + c] = conv1_w[c * 9 + 7] * s1;
            p1[384 + c] = bn1_b[c] - bn1_m[c] * s1;
        }
    }

#pragma unroll
    for (int i = 0; i < 8; ++i) {
        int r = w * 8 + i;
        const float* xr = x + (row0 + r) * C_;
        float2 v = *(const float2*)&xr[lane * 2];
        float ss = v.x * v.x + v.y * v.y;
#pragma unroll
        for (int m = 1; m < 64; m <<= 1) ss += __shfl_xor(ss, m, 64);
        float rn = 1.0f / fmaxf(sqrtf(ss), 1e-12f);
        xt[r][lane] = pack2(v.x * rn, v.y * rn);
    }
    __syncthreads();

    if (tloc <= Lb) {
        // consumed by fused kernel (conv halo reaches chunk Lb/32): store it
        uint4* dst = (uint4*)(xtm + (size_t)blockIdx.x * 4096);
#pragma unroll
        for (int uu = 0; uu < 2; ++uu) {
            int u = tid * 2 + uu;              // 0..511
            int c = u >> 2, j = u & 3;
            int cw = c >> 1, sh = (c & 1) * 16;
            uint o[4];
#pragma unroll
            for (int q = 0; q < 4; ++q) {
                uint lo = (xt[j * 8 + q * 2][cw] >> sh) & 0xffffu;
                uint hi = (xt[j * 8 + q * 2 + 1][cw] >> sh) & 0xffffu;
                o[q] = lo | (hi << 16);
            }
            uint4 v; v.x = o[0]; v.y = o[1]; v.z = o[2]; v.w = o[3];
            dst[u] = v;
        }
    }
    if (tloc >= Lb && w == 0) {
        // analytic masked region [Lb, T): contribution = mcs/64
        float sx = 0.f, sy = 0.f;
#pragma unroll 8
        for (int r = 0; r < 32; ++r) {
            uint u = xt[r][lane];
            sx += bfu((ushort)(u & 0xffffu));
            sy += bfu((ushort)(u >> 16));
        }
        atomicAdd(&mcs[n * C_ + lane * 2], sx);
        atomicAdd(&mcs[n * C_ + lane * 2 + 1], sy);
    }
}

// Fused: conv -> logits MFMA -> softmax -> a in LDS -> vlad MFMA (af from LDS,
// bfv from xtm/L2) -> private partials. n-fast index: live blocks occupy the
// contiguous low grid range, so CUs fill with live work immediately.
__global__ __launch_bounds__(256, 3) void fused_k(
    const ushort* __restrict__ xtm,
    const float* __restrict__ conv2_b,
    const float* __restrict__ bn2_g, const float* __restrict__ bn2_b,
    const float* __restrict__ bn2_m, const float* __restrict__ bn2_v,
    const int* __restrict__ length,
    const ushort* __restrict__ w2t, const float* __restrict__ p1,
    float* __restrict__ part, float* __restrict__ asum) {

    __shared__ __align__(16) ushort w2l[8192];           // 16 KB
    __shared__ __align__(16) ushort h_s[4][16 * 136];    // 17.4 KB
    __shared__ __align__(16) uint4 ab[2][64 * 5];        // 10.2 KB

    const int tid = threadIdx.x;
    const int lane = tid & 63;
    const int w = tid >> 6;
    const int fr = lane & 15, fg = lane >> 4;
    const int tile = w >> 1, half = w & 1;
    const int n = blockIdx.x & (N_ - 1);     // n-fast
    const int blk = blockIdx.x >> 4;
    const int tb = blk * TPB_A;
    const int L = length[n];
    if (tb >= L) return;                   // analytic region (mcs)

    const ushort* xtm_n = xtm + (size_t)n * 256 * 4096;

    {
        const uint4* w2g = (const uint4*)w2t;
        uint4* w2d = (uint4*)w2l;
#pragma unroll
        for (int i = 0; i < 4; ++i) w2d[tid + i * 256] = w2g[tid + i * 256];
    }

    float wa[2], wbv[2], wcv[2], sbv[2];
#pragma unroll
    for (int p = 0; p < 2; ++p) {
        int c = lane + p * 64;
        wa[p] = p1[c]; wbv[p] = p1[128 + c];
        wcv[p] = p1[256 + c]; sbv[p] = p1[384 + c];
    }

    float sh2r[16];
#pragma unroll
    for (int m = 0; m < 4; ++m)
#pragma unroll
        for (int r = 0; r < 4; ++r) {
            int k = m * 16 + fg * 4 + r;
            float s = bn2_g[k] * rsqrtf(bn2_v[k] + 1e-5f);
            sh2r[m * 4 + r] = s * conv2_b[k] + bn2_b[k] - bn2_m[k] * s;
        }

    short8 onesf;
    {
        short f = (fr == 0) ? (short)0x3F80 : (short)0;
#pragma unroll
        for (int j = 0; j < 8; ++j) onesf[j] = f;
    }

    f32x4 accB[9];
#pragma unroll
    for (int cb = 0; cb < 9; ++cb) accB[cb] = (f32x4){0.f, 0.f, 0.f, 0.f};

    __syncthreads();

    for (int s = 0; s < TPB_A / 64; ++s) {
        const int tbs = tb + s * 64;
        const int tcs = (tbs >> 5) + tile;
        const ushort* xch = xtm_n + (size_t)tcs * 4096;
        const int t0 = tbs + tile * 32 + half * 16;

        if (t0 < L) {
            // ---- conv: lane owns c = lane, lane+64; 16 t in registers ----
            ushort* hw = h_s[w];
#pragma unroll
            for (int p = 0; p < 2; ++p) {
                const int c = lane + p * 64;
                short8 x0 = *(const short8*)&xch[c * 32 + half * 16];
                short8 x1 = *(const short8*)&xch[c * 32 + half * 16 + 8];
                float av[18];
                av[0] = 0.f; av[17] = 0.f;
                if (t0 > 0)
                    av[0] = bfu(half ? xch[c * 32 + 15] : xch[c * 32 - 4096 + 31]);
                if (t0 + 16 < T_)
                    av[17] = bfu(half ? xch[c * 32 + 4096] : xch[c * 32 + 16]);
#pragma unroll
                for (int j = 0; j < 8; ++j) {
                    av[1 + j] = bfu((ushort)x0[j]);
                    av[9 + j] = bfu((ushort)x1[j]);
                }
                float WA = wa[p], WB = wbv[p], WC = wcv[p], SB = sbv[p];
#pragma unroll
                for (int j = 0; j < 16; ++j)
                    hw[j * 136 + c] = (ushort)bfr(
                        fmaxf(0.f, av[j] * WA + av[j + 1] * WB + av[j + 2] * WC + SB));
            }
            // ---- logits MFMA (w2 from LDS; all 16 B-columns real) ----
            f32x4 accL[4];
#pragma unroll
            for (int m = 0; m < 4; ++m) accL[m] = (f32x4){0.f, 0.f, 0.f, 0.f};
            const ushort* hbp = h_s[w] + fr * 136 + fg * 8;
#pragma unroll
            for (int q = 0; q < 4; ++q) {
                short8 hf = *(const short8*)(hbp + q * 32);
                short8 w0 = *(const short8*)&w2l[((0 * 4 + q) * 64 + lane) * 8];
                short8 w1 = *(const short8*)&w2l[((1 * 4 + q) * 64 + lane) * 8];
                short8 w2f = *(const short8*)&w2l[((2 * 4 + q) * 64 + lane) * 8];
                short8 w3 = *(const short8*)&w2l[((3 * 4 + q) * 64 + lane) * 8];
                accL[0] = __builtin_amdgcn_mfma_f32_16x16x32_bf16(w0, hf, accL[0], 0, 0, 0);
                accL[1] = __builtin_amdgcn_mfma_f32_16x16x32_bf16(w1, hf, accL[1], 0, 0, 0);
                accL[2] = __builtin_amdgcn_mfma_f32_16x16x32_bf16(w2f, hf, accL[2], 0, 0, 0);
                accL[3] = __builtin_amdgcn_mfma_f32_16x16x32_bf16(w3, hf, accL[3], 0, 0, 0);
            }
            // ---- bn2 + relu + mask + softmax over k (t = t0 + fr, all lanes) ----
            {
                int t = t0 + fr;
                float v[16];
#pragma unroll
                for (int m = 0; m < 4; ++m)
#pragma unroll
                    for (int r = 0; r < 4; ++r)
                        v[m * 4 + r] = fmaxf(0.f, accL[m][r] + sh2r[m * 4 + r]);
                if (t < L) {
                    float mx = v[0];
#pragma unroll
                    for (int i = 1; i < 16; ++i) mx = fmaxf(mx, v[i]);
                    mx = fmaxf(mx, __shfl_xor(mx, 16, 64));
                    mx = fmaxf(mx, __shfl_xor(mx, 32, 64));
                    float se = 0.f;
#pragma unroll
                    for (int i = 0; i < 16; ++i) { v[i] = __expf(v[i] - mx); se += v[i]; }
                    se += __shfl_xor(se, 16, 64);
                    se += __shfl_xor(se, 32, 64);
                    float inv = 1.0f / se;
#pragma unroll
                    for (int i = 0; i < 16; ++i) v[i] *= inv;
                } else {
#pragma unroll
                    for (int i = 0; i < 16; ++i) v[i] = 0.015625f;
                }
                const int jq = half * 2 + (fr >> 3);
                const int te = fr & 7;
#pragma unroll
                for (int m = 0; m < 4; ++m)
#pragma unroll
                    for (int r = 0; r < 4; ++r) {
                        int k = m * 16 + fg * 4 + r;
                        ((ushort*)&ab[tile][k * 5 + jq])[te] = (ushort)bfr(v[m * 4 + r]);
                    }
            }
        } else {
            // masked wave (t in [L, Lb)): a = 1/64 exactly (2 quads)
            uint4 cfill;
            cfill.x = cfill.y = cfill.z = cfill.w = 0x3C803C80u;
            ab[tile][lane * 5 + half * 2] = cfill;
            ab[tile][lane * 5 + half * 2 + 1] = cfill;
        }
        __syncthreads();
        // ---- vlad MFMA: af from LDS, bfv from xtm (L2-hot) ----
#pragma unroll
        for (int cc = 0; cc < 2; ++cc) {
            const ushort* xc2 = xtm_n + (size_t)((tbs >> 5) + cc) * 4096;
            short8 af = *(const short8*)&ab[cc][(w * 16 + fr) * 5 + fg];
#pragma unroll
            for (int cb = 0; cb < 8; ++cb) {
                short8 bfv = *(const short8*)&xc2[(cb * 16 + fr) * 32 + fg * 8];
                accB[cb] = __builtin_amdgcn_mfma_f32_16x16x32_bf16(af, bfv, accB[cb], 0, 0, 0);
            }
            accB[8] = __builtin_amdgcn_mfma_f32_16x16x32_bf16(af, onesf, accB[8], 0, 0, 0);
        }
        __syncthreads();
    }

    float* pr = part + (size_t)(n * BPN_A + blk) * (K_ * C_);
#pragma unroll
    for (int cb = 0; cb < 8; ++cb)
#pragma unroll
        for (int r = 0; r < 4; ++r)
            pr[(w * 16 + fg * 4 + r) * C_ + cb * 16 + fr] = accB[cb][r];
    if (fr == 0) {
#pragma unroll
        for (int r = 0; r < 4; ++r)
            atomicAdd(&asum[n * K_ + w * 16 + fg * 4 + r], accB[8][r]);
    }
}

// fused reduce + finalize: live partials + analytic masked term, intra-norm,
// analytic global norm (K unit rows -> 1/sqrt(K) = 1/8 folded in).
__global__ void finalize2_k(const float* __restrict__ cent,
                            const float* __restrict__ part,
                            const float* __restrict__ asum,
                            const float* __restrict__ mcs,
                            const int* __restrict__ length,
                            float* __restrict__ out) {
    int row = blockIdx.x * 4 + (threadIdx.x >> 6);  // n*64 + k
    int lane = threadIdx.x & 63;
    int n = row >> 6, k = row & 63;
    const int L = length[n];
    const int nlive = (L + 127) >> 7;      // live fused blocks
    const float* pr = part + (size_t)n * BPN_A * (K_ * C_) + k * C_;
    float y0 = 0.f, y1 = 0.f;
#pragma unroll 4
    for (int b = 0; b < nlive; ++b) {
        y0 += pr[(size_t)b * (K_ * C_) + lane];
        y1 += pr[(size_t)b * (K_ * C_) + lane + 64];
    }
    y0 += 0.015625f * mcs[n * C_ + lane];
    y1 += 0.015625f * mcs[n * C_ + lane + 64];
    float as = asum[row] + (float)(T_ - nlive * TPB_A) * 0.015625f;
    y0 -= as * cent[k * C_ + lane];
    y1 -= as * cent[k * C_ + lane + 64];
    float ss = y0 * y0 + y1 * y1;
#pragma unroll
    for (int m = 1; m < 64; m <<= 1) ss += __shfl_xor(ss, m, 64);
    float rs = 0.125f / fmaxf(sqrtf(ss), 1e-12f);   // intra-norm x global 1/8
    out[(size_t)row * C_ + lane] = y0 * rs;
    out[(size_t)row * C_ + lane + 64] = y1 * rs;
}

extern "C" void kernel_launch(void* const* d_in, const int* in_sizes, int n_in,
                              void* d_out, int out_size, void* d_ws, size_t ws_size,
                              hipStream_t stream) {
    const float* x       = (const float*)d_in[0];
    const float* conv1_w = (const float*)d_in[1];
    const float* bn1_g   = (const float*)d_in[2];
    const float* bn1_b   = (const float*)d_in[3];
    const float* bn1_m   = (const float*)d_in[4];
    const float* bn1_v   = (const float*)d_in[5];
    const float* conv2_w = (const float*)d_in[6];
    const float* conv2_b = (const float*)d_in[7];
    const float* bn2_g   = (const float*)d_in[8];
    const float* bn2_b   = (const float*)d_in[9];
    const float* bn2_m   = (const float*)d_in[10];
    const float* bn2_v   = (const float*)d_in[11];
    const float* cent    = (const float*)d_in[12];
    const int*   length  = (const int*)d_in[13];
    float* out = (float*)d_out;
    float* ws  = (float*)d_ws;

    hipMemsetAsync(ws, 0, NW_ZBYTES, stream);  // zero asum + mcs
    xnorm_k<<<N_ * T_ / 32, 256, 0, stream>>>(
        x, (ushort*)(ws + NW_XTM), length, ws + NW_MCS,
        conv1_w, bn1_g, bn1_b, bn1_m, bn1_v, conv2_w, bn2_g, bn2_v,
        (ushort*)(ws + NW_W2F), ws + NW_P1);
    fused_k<<<N_ * BPN_A, 256, 0, stream>>>(
        (const ushort*)(ws + NW_XTM), conv2_b, bn2_g, bn2_b, bn2_m, bn2_v,
        length, (const ushort*)(ws + NW_W2F), ws + NW_P1,
        ws + NW_PART, ws + NW_ASUM);
    finalize2_k<<<(N_ * K_) / 4, 256, 0, stream>>>(
        cent, ws + NW_PART, ws + NW_ASUM, ws + NW_MCS, length, out);
}

// Round 19
// 73.731 us; speedup vs baseline: 1.2632x; 1.0764x over previous
//
#include <hip/hip_runtime.h>
#include <math.h>

#define N_ 16
#define T_ 8192
#define C_ 128
#define K_ 64

#define TPB_A 128      // t per fused block
#define BPN_A 64       // fused blocks per n

// ws layout in floats (67.15 MB; ws proven 268 MB by harness poison fills)
#define NW_ASUM 0              // 1024
#define NW_MCS  2048           // N*C = 2048 -> 4096  (masked colsum)
#define NW_ZBYTES (4096 * 4)   // memset region covers asum+mcs
#define NW_W2F  4096           // 4096 floats (8192 bf16)
#define NW_P1   8192           // 512 -> 8704, pad to 8960
#define NW_XTM  8960           // N*T*C bf16 = 8388608 floats -> 8397568
#define NW_PART 8397568        // N*BPN_A*K*C = 8388608 floats -> 16786176
#define NW_TOTAL 16786176

typedef __attribute__((ext_vector_type(8))) short short8;
typedef __attribute__((ext_vector_type(4))) float f32x4;

__device__ __forceinline__ uint bfr(float f) {          // fp32 -> bf16 (RNE)
    uint u = __float_as_uint(f);
    return (u + 0x7fffu + ((u >> 16) & 1u)) >> 16;
}
__device__ __forceinline__ uint pack2(float lo, float hi) {
    return bfr(lo) | (bfr(hi) << 16);
}
__device__ __forceinline__ float bfu(ushort u) {
    return __uint_as_float(((uint)u) << 16);
}

// Normalize rows, emit xn bf16 t-minor chunks [chunk=32t][128c][32t] (chunks
// up to Lb + halo), accumulate masked-region (t >= Lb) colsum into mcs.
// Blocks 0..3 additionally build the w2 fragment table + conv1/bn1 params
// (consumed only by fused_k, which launches after this kernel completes).
__global__ __launch_bounds__(256, 8) void xnorm_k(
    const float* __restrict__ x, ushort* __restrict__ xtm,
    const int* __restrict__ length, float* __restrict__ mcs,
    const float* __restrict__ conv1_w,
    const float* __restrict__ bn1_g, const float* __restrict__ bn1_b,
    const float* __restrict__ bn1_m, const float* __restrict__ bn1_v,
    const float* __restrict__ conv2_w,
    const float* __restrict__ bn2_g, const float* __restrict__ bn2_v,
    ushort* __restrict__ w2t, float* __restrict__ p1) {
    __shared__ uint xt[32][64];            // packed c-pairs, [t][c2]
    const int tid = threadIdx.x;
    const int lane = tid & 63;
    const int w = tid >> 6;
    const int n = blockIdx.x >> 8;
    const int tloc = (blockIdx.x & 255) * 32;
    const size_t row0 = (size_t)blockIdx.x * 32;
    const int L = length[n];
    const int Lb = ((L + 127) >> 7) << 7;  // live-block coverage [0, Lb)

    // ---- setup (blocks 0..3): constant tables for fused_k ----
    if (blockIdx.x < 4) {
        const int gt = blockIdx.x * 256 + tid;   // 0..1023
        for (int idx = gt; idx < 8192; idx += 1024) {
            int j = idx & 7;
            int ln = (idx >> 3) & 63;
            int mq = idx >> 9;
            int m = mq >> 2, q = mq & 3;
            int fr = ln & 15, fg = ln >> 4;
            int k = m * 16 + fr;
            float sck = bn2_g[k] * rsqrtf(bn2_v[k] + 1e-5f);
            float v = conv2_w[k * C_ + q * 32 + fg * 8 + j] * sck;
            w2t[idx] = (ushort)bfr(v);
        }
        for (int c = gt; c < C_; c += 1024) {
            float s1 = bn1_g[c] * rsqrtf(bn1_v[c] + 1e-5f);
            p1[c]       = conv1_w[c * 9 + 1] * s1;
            p1[128 + c] = conv1_w[c * 9 + 4] * s1;
            p1[256 + c] = conv1_w[c * 9 + 7] * s1;
            p1[384 + c] = bn1_b[c] - bn1_m[c] * s1;
        }
    }

#pragma unroll
    for (int i = 0; i < 8; ++i) {
        int r = w * 8 + i;
        const float* xr = x + (row0 + r) * C_;
        float2 v = *(const float2*)&xr[lane * 2];
        float ss = v.x * v.x + v.y * v.y;
#pragma unroll
        for (int m = 1; m < 64; m <<= 1) ss += __shfl_xor(ss, m, 64);
        float rn = 1.0f / fmaxf(sqrtf(ss), 1e-12f);
        xt[r][lane] = pack2(v.x * rn, v.y * rn);
    }
    __syncthreads();

    if (tloc <= Lb) {
        // consumed by fused kernel (conv halo reaches chunk Lb/32): store it
        uint4* dst = (uint4*)(xtm + (size_t)blockIdx.x * 4096);
#pragma unroll
        for (int uu = 0; uu < 2; ++uu) {
            int u = tid * 2 + uu;              // 0..511
            int c = u >> 2, j = u & 3;
            int cw = c >> 1, sh = (c & 1) * 16;
            uint o[4];
#pragma unroll
            for (int q = 0; q < 4; ++q) {
                uint lo = (xt[j * 8 + q * 2][cw] >> sh) & 0xffffu;
                uint hi = (xt[j * 8 + q * 2 + 1][cw] >> sh) & 0xffffu;
                o[q] = lo | (hi << 16);
            }
            uint4 v; v.x = o[0]; v.y = o[1]; v.z = o[2]; v.w = o[3];
            dst[u] = v;
        }
    }
    if (tloc >= Lb && w == 0) {
        // analytic masked region [Lb, T): contribution = mcs/64
        float sx = 0.f, sy = 0.f;
#pragma unroll 8
        for (int r = 0; r < 32; ++r) {
            uint u = xt[r][lane];
            sx += bfu((ushort)(u & 0xffffu));
            sy += bfu((ushort)(u >> 16));
        }
        atomicAdd(&mcs[n * C_ + lane * 2], sx);
        atomicAdd(&mcs[n * C_ + lane * 2 + 1], sy);
    }
}

// Fused: conv -> logits MFMA -> softmax -> a in LDS -> vlad MFMA (af from LDS,
// bfv from xtm/L2) -> private partials. Blocks with tb >= L return early.
// n-slow index (n = bid>>6): consecutive blocks share n + adjacent t-chunks
// for L2 locality (n-fast variant measured -7 us, round 18).
__global__ __launch_bounds__(256, 3) void fused_k(
    const ushort* __restrict__ xtm,
    const float* __restrict__ conv2_b,
    const float* __restrict__ bn2_g, const float* __restrict__ bn2_b,
    const float* __restrict__ bn2_m, const float* __restrict__ bn2_v,
    const int* __restrict__ length,
    const ushort* __restrict__ w2t, const float* __restrict__ p1,
    float* __restrict__ part, float* __restrict__ asum) {

    __shared__ __align__(16) ushort w2l[8192];           // 16 KB
    __shared__ __align__(16) ushort h_s[4][16 * 136];    // 17.4 KB
    __shared__ __align__(16) uint4 ab[2][64 * 5];        // 10.2 KB

    const int tid = threadIdx.x;
    const int lane = tid & 63;
    const int w = tid >> 6;
    const int fr = lane & 15, fg = lane >> 4;
    const int tile = w >> 1, half = w & 1;
    const int n = blockIdx.x >> 6;
    const int blk = blockIdx.x & (BPN_A - 1);
    const int tb = blk * TPB_A;
    const int L = length[n];
    if (tb >= L) return;                   // analytic region (mcs)

    const ushort* xtm_n = xtm + (size_t)n * 256 * 4096;

    {
        const uint4* w2g = (const uint4*)w2t;
        uint4* w2d = (uint4*)w2l;
#pragma unroll
        for (int i = 0; i < 4; ++i) w2d[tid + i * 256] = w2g[tid + i * 256];
    }

    float wa[2], wbv[2], wcv[2], sbv[2];
#pragma unroll
    for (int p = 0; p < 2; ++p) {
        int c = lane + p * 64;
        wa[p] = p1[c]; wbv[p] = p1[128 + c];
        wcv[p] = p1[256 + c]; sbv[p] = p1[384 + c];
    }

    float sh2r[16];
#pragma unroll
    for (int m = 0; m < 4; ++m)
#pragma unroll
        for (int r = 0; r < 4; ++r) {
            int k = m * 16 + fg * 4 + r;
            float s = bn2_g[k] * rsqrtf(bn2_v[k] + 1e-5f);
            sh2r[m * 4 + r] = s * conv2_b[k] + bn2_b[k] - bn2_m[k] * s;
        }

    short8 onesf;
    {
        short f = (fr == 0) ? (short)0x3F80 : (short)0;
#pragma unroll
        for (int j = 0; j < 8; ++j) onesf[j] = f;
    }

    f32x4 accB[9];
#pragma unroll
    for (int cb = 0; cb < 9; ++cb) accB[cb] = (f32x4){0.f, 0.f, 0.f, 0.f};

    __syncthreads();

    for (int s = 0; s < TPB_A / 64; ++s) {
        const int tbs = tb + s * 64;
        const int tcs = (tbs >> 5) + tile;
        const ushort* xch = xtm_n + (size_t)tcs * 4096;
        const int t0 = tbs + tile * 32 + half * 16;

        if (t0 < L) {
            // ---- conv: lane owns c = lane, lane+64; 16 t in registers ----
            ushort* hw = h_s[w];
#pragma unroll
            for (int p = 0; p < 2; ++p) {
                const int c = lane + p * 64;
                short8 x0 = *(const short8*)&xch[c * 32 + half * 16];
                short8 x1 = *(const short8*)&xch[c * 32 + half * 16 + 8];
                float av[18];
                av[0] = 0.f; av[17] = 0.f;
                if (t0 > 0)
                    av[0] = bfu(half ? xch[c * 32 + 15] : xch[c * 32 - 4096 + 31]);
                if (t0 + 16 < T_)
                    av[17] = bfu(half ? xch[c * 32 + 4096] : xch[c * 32 + 16]);
#pragma unroll
                for (int j = 0; j < 8; ++j) {
                    av[1 + j] = bfu((ushort)x0[j]);
                    av[9 + j] = bfu((ushort)x1[j]);
                }
                float WA = wa[p], WB = wbv[p], WC = wcv[p], SB = sbv[p];
#pragma unroll
                for (int j = 0; j < 16; ++j)
                    hw[j * 136 + c] = (ushort)bfr(
                        fmaxf(0.f, av[j] * WA + av[j + 1] * WB + av[j + 2] * WC + SB));
            }
            // ---- logits MFMA (w2 from LDS; all 16 B-columns real) ----
            f32x4 accL[4];
#pragma unroll
            for (int m = 0; m < 4; ++m) accL[m] = (f32x4){0.f, 0.f, 0.f, 0.f};
            const ushort* hbp = h_s[w] + fr * 136 + fg * 8;
#pragma unroll
            for (int q = 0; q < 4; ++q) {
                short8 hf = *(const short8*)(hbp + q * 32);
                short8 w0 = *(const short8*)&w2l[((0 * 4 + q) * 64 + lane) * 8];
                short8 w1 = *(const short8*)&w2l[((1 * 4 + q) * 64 + lane) * 8];
                short8 w2f = *(const short8*)&w2l[((2 * 4 + q) * 64 + lane) * 8];
                short8 w3 = *(const short8*)&w2l[((3 * 4 + q) * 64 + lane) * 8];
                accL[0] = __builtin_amdgcn_mfma_f32_16x16x32_bf16(w0, hf, accL[0], 0, 0, 0);
                accL[1] = __builtin_amdgcn_mfma_f32_16x16x32_bf16(w1, hf, accL[1], 0, 0, 0);
                accL[2] = __builtin_amdgcn_mfma_f32_16x16x32_bf16(w2f, hf, accL[2], 0, 0, 0);
                accL[3] = __builtin_amdgcn_mfma_f32_16x16x32_bf16(w3, hf, accL[3], 0, 0, 0);
            }
            // ---- bn2 + relu + mask + softmax over k (t = t0 + fr, all lanes) ----
            {
                int t = t0 + fr;
                float v[16];
#pragma unroll
                for (int m = 0; m < 4; ++m)
#pragma unroll
                    for (int r = 0; r < 4; ++r)
                        v[m * 4 + r] = fmaxf(0.f, accL[m][r] + sh2r[m * 4 + r]);
                if (t < L) {
                    float mx = v[0];
#pragma unroll
                    for (int i = 1; i < 16; ++i) mx = fmaxf(mx, v[i]);
                    mx = fmaxf(mx, __shfl_xor(mx, 16, 64));
                    mx = fmaxf(mx, __shfl_xor(mx, 32, 64));
                    float se = 0.f;
#pragma unroll
                    for (int i = 0; i < 16; ++i) { v[i] = __expf(v[i] - mx); se += v[i]; }
                    se += __shfl_xor(se, 16, 64);
                    se += __shfl_xor(se, 32, 64);
                    float inv = 1.0f / se;
#pragma unroll
                    for (int i = 0; i < 16; ++i) v[i] *= inv;
                } else {
#pragma unroll
                    for (int i = 0; i < 16; ++i) v[i] = 0.015625f;
                }
                const int jq = half * 2 + (fr >> 3);
                const int te = fr & 7;
#pragma unroll
                for (int m = 0; m < 4; ++m)
#pragma unroll
                    for (int r = 0; r < 4; ++r) {
                        int k = m * 16 + fg * 4 + r;
                        ((ushort*)&ab[tile][k * 5 + jq])[te] = (ushort)bfr(v[m * 4 + r]);
                    }
            }
        } else {
            // masked wave (t in [L, Lb)): a = 1/64 exactly (2 quads)
            uint4 cfill;
            cfill.x = cfill.y = cfill.z = cfill.w = 0x3C803C80u;
            ab[tile][lane * 5 + half * 2] = cfill;
            ab[tile][lane * 5 + half * 2 + 1] = cfill;
        }
        __syncthreads();
        // ---- vlad MFMA: af from LDS, bfv from xtm (L2-hot) ----
#pragma unroll
        for (int cc = 0; cc < 2; ++cc) {
            const ushort* xc2 = xtm_n + (size_t)((tbs >> 5) + cc) * 4096;
            short8 af = *(const short8*)&ab[cc][(w * 16 + fr) * 5 + fg];
#pragma unroll
            for (int cb = 0; cb < 8; ++cb) {
                short8 bfv = *(const short8*)&xc2[(cb * 16 + fr) * 32 + fg * 8];
                accB[cb] = __builtin_amdgcn_mfma_f32_16x16x32_bf16(af, bfv, accB[cb], 0, 0, 0);
            }
            accB[8] = __builtin_amdgcn_mfma_f32_16x16x32_bf16(af, onesf, accB[8], 0, 0, 0);
        }
        __syncthreads();
    }

    float* pr = part + (size_t)(n * BPN_A + blk) * (K_ * C_);
#pragma unroll
    for (int cb = 0; cb < 8; ++cb)
#pragma unroll
        for (int r = 0; r < 4; ++r)
            pr[(w * 16 + fg * 4 + r) * C_ + cb * 16 + fr] = accB[cb][r];
    if (fr == 0) {
#pragma unroll
        for (int r = 0; r < 4; ++r)
            atomicAdd(&asum[n * K_ + w * 16 + fg * 4 + r], accB[8][r]);
    }
}

// fused reduce + finalize: live partials + analytic masked term, intra-norm,
// analytic global norm (K unit rows -> 1/sqrt(K) = 1/8 folded in).
__global__ void finalize2_k(const float* __restrict__ cent,
                            const float* __restrict__ part,
                            const float* __restrict__ asum,
                            const float* __restrict__ mcs,
                            const int* __restrict__ length,
                            float* __restrict__ out) {
    int row = blockIdx.x * 4 + (threadIdx.x >> 6);  // n*64 + k
    int lane = threadIdx.x & 63;
    int n = row >> 6, k = row & 63;
    const int L = length[n];
    const int nlive = (L + 127) >> 7;      // live fused blocks
    const float* pr = part + (size_t)n * BPN_A * (K_ * C_) + k * C_;
    float y0 = 0.f, y1 = 0.f;
#pragma unroll 4
    for (int b = 0; b < nlive; ++b) {
        y0 += pr[(size_t)b * (K_ * C_) + lane];
        y1 += pr[(size_t)b * (K_ * C_) + lane + 64];
    }
    y0 += 0.015625f * mcs[n * C_ + lane];
    y1 += 0.015625f * mcs[n * C_ + lane + 64];
    float as = asum[row] + (float)(T_ - nlive * TPB_A) * 0.015625f;
    y0 -= as * cent[k * C_ + lane];
    y1 -= as * cent[k * C_ + lane + 64];
    float ss = y0 * y0 + y1 * y1;
#pragma unroll
    for (int m = 1; m < 64; m <<= 1) ss += __shfl_xor(ss, m, 64);
    float rs = 0.125f / fmaxf(sqrtf(ss), 1e-12f);   // intra-norm x global 1/8
    out[(size_t)row * C_ + lane] = y0 * rs;
    out[(size_t)row * C_ + lane + 64] = y1 * rs;
}

extern "C" void kernel_launch(void* const* d_in, const int* in_sizes, int n_in,
                              void* d_out, int out_size, void* d_ws, size_t ws_size,
                              hipStream_t stream) {
    const float* x       = (const float*)d_in[0];
    const float* conv1_w = (const float*)d_in[1];
    const float* bn1_g   = (const float*)d_in[2];
    const float* bn1_b   = (const float*)d_in[3];
    const float* bn1_m   = (const float*)d_in[4];
    const float* bn1_v   = (const float*)d_in[5];
    const float* conv2_w = (const float*)d_in[6];
    const float* conv2_b = (const float*)d_in[7];
    const float* bn2_g   = (const float*)d_in[8];
    const float* bn2_b   = (const float*)d_in[9];
    const float* bn2_m   = (const float*)d_in[10];
    const float* bn2_v   = (const float*)d_in[11];
    const float* cent    = (const float*)d_in[12];
    const int*   length  = (const int*)d_in[13];
    float* out = (float*)d_out;
    float* ws  = (float*)d_ws;

    hipMemsetAsync(ws, 0, NW_ZBYTES, stream);  // zero asum + mcs
    xnorm_k<<<N_ * T_ / 32, 256, 0, stream>>>(
        x, (ushort*)(ws + NW_XTM), length, ws + NW_MCS,
        conv1_w, bn1_g, bn1_b, bn1_m, bn1_v, conv2_w, bn2_g, bn2_v,
        (ushort*)(ws + NW_W2F), ws + NW_P1);
    fused_k<<<N_ * BPN_A, 256, 0, stream>>>(
        (const ushort*)(ws + NW_XTM), conv2_b, bn2_g, bn2_b, bn2_m, bn2_v,
        length, (const ushort*)(ws + NW_W2F), ws + NW_P1,
        ws + NW_PART, ws + NW_ASUM);
    finalize2_k<<<(N_ * K_) / 4, 256, 0, stream>>>(
        cent, ws + NW_PART, ws + NW_ASUM, ws + NW_MCS, length, out);
}